// Round 11
// baseline (528.174 us; speedup 1.0000x reference)
//
#include <hip/hip_runtime.h>
#include <math.h>

typedef _Float16 Hh;
typedef __attribute__((ext_vector_type(8))) _Float16 half8;
typedef __attribute__((ext_vector_type(4))) _Float16 half4;
typedef __attribute__((ext_vector_type(4))) float float4v;

#define B_ 2
#define H_ 16
#define N_ 2048
#define D_ 64
#define ND_ (N_*D_)
#define C1 0.04508422f   // (1/32)*log2(e); softmax in base-2 throughout

// Barrier without the vmcnt(0) drain (LDS-only dependencies).
#define BAR() asm volatile("s_waitcnt lgkmcnt(0)\n\ts_barrier" ::: "memory")

// attend LDS layouts (i-tile 32, j-tile 32):
// Ebuf: [j(32)][i(32)][f(16+4pad)]  j-stride 644, i-stride 20 halves (41216 B)
#define EB_JS 644
#define EB_IS 20
// Pm: [e(16)][i(32)][j(32+4pad)]    e-stride 1156, i-stride 36 halves (36992 B)
#define PM_ES 1156
#define PM_IS 36

// ---------------------------------------------------------------------------
// K1: prep. (R10 verbatim)
// ---------------------------------------------------------------------------
__global__ __launch_bounds__(256) void prep_kernel(const float* __restrict__ q,
    const float* __restrict__ k, const float* __restrict__ v,
    const float* __restrict__ Wpre,
    Hh* __restrict__ qb, Hh* __restrict__ kb, Hh* __restrict__ vt2,
    float4* __restrict__ out4, float4* __restrict__ lacc4)
{
    int tid = threadIdx.x;
    int bid = blockIdx.x;
    if (bid < 512) {
        __shared__ float wsh[256];
        wsh[tid] = Wpre[tid];
        __syncthreads();
        int tensor = bid >> 8;
        int g = ((bid & 255) << 8) | tid;     // 0 .. 65535
        int b = g >> 15;
        int r = g & 32767;                    // (n,d4): n*16 + d4
        const float4* src = (const float4*)(tensor ? k : q);
        Hh* dst = tensor ? kb : qb;
        float4 x[16];
        #pragma unroll
        for (int f=0; f<16; f++) x[f] = src[(size_t)(b*16+f)*32768 + r];
        #pragma unroll
        for (int e=0; e<16; e++) {
            float4 a = make_float4(0.f,0.f,0.f,0.f);
            #pragma unroll
            for (int f=0; f<16; f++) {
                float wv = wsh[e*16+f];
                a.x += wv*x[f].x; a.y += wv*x[f].y; a.z += wv*x[f].z; a.w += wv*x[f].w;
            }
            half4 hv; hv[0]=(Hh)a.x; hv[1]=(Hh)a.y; hv[2]=(Hh)a.z; hv[3]=(Hh)a.w;
            *(half4*)(dst + (size_t)(b*16+e)*ND_ + (size_t)r*4) = hv;
        }
    } else if (bid < 768) {
        __shared__ Hh tile[64*48];            // [d][j], stride 48 halves
        int tb = bid - 512;                   // 0..255
        int be = tb >> 3;                     // 0..31
        int jtg = tb & 7;
        const float4* v4 = (const float4*)v;
        for (int u=0; u<8; u++) {
            int jt = jtg*8 + u;               // 0..63
            #pragma unroll
            for (int p=0; p<2; p++) {
                int j = p*16 + (tid>>4);
                int d4 = tid & 15;
                float4 val = v4[(size_t)be*32768 + (size_t)(jt*32+j)*16 + d4];
                tile[(d4*4+0)*48 + j] = (Hh)val.x;
                tile[(d4*4+1)*48 + j] = (Hh)val.y;
                tile[(d4*4+2)*48 + j] = (Hh)val.z;
                tile[(d4*4+3)*48 + j] = (Hh)val.w;
            }
            BAR();
            {
                int d = tid >> 2;
                int jc = (tid & 3) * 8;
                half8 o;
                #pragma unroll
                for (int z=0; z<8; z++) o[z] = tile[d*48 + jc + z];
                *(half8*)(vt2 + ((size_t)(be*64) + jt)*2048 + (size_t)tid*8) = o;
            }
            BAR();
        }
    } else {
        int zid = (bid - 768) * 256 + tid;    // 0 .. 262143
        float4 zz = make_float4(0.f,0.f,0.f,0.f);
        #pragma unroll
        for (int u=0; u<4; u++) out4[(size_t)u*262144 + zid] = zz;
        if (zid < 16384) lacc4[zid] = zz;
    }
}

// ---------------------------------------------------------------------------
// K2: denominators. (R10 verbatim)
// ---------------------------------------------------------------------------
__global__ __launch_bounds__(512) void denom_kernel(const Hh* __restrict__ qb,
    const Hh* __restrict__ kb, float* __restrict__ lacc_g)
{
    int bid = blockIdx.x;
    int s = bid & 7;
    int idx = 127 - (bid >> 3);
    int b = idx & 1, it = idx >> 1;          // it 0..63
    if (s > it) return;

    int i0 = it * 32;
    int tid = threadIdx.x;
    int lane = tid & 63, w = tid >> 6;
    int qd = lane >> 4, c = lane & 15;
    int f0 = 2*w;

    half8 aq[2][2][2];
    #pragma unroll
    for (int fi=0; fi<2; fi++) {
        #pragma unroll
        for (int ig=0; ig<2; ig++) {
            const Hh* qr = qb + (size_t)((b*16+f0+fi)*N_ + i0 + ig*16 + c)*64 + qd*8;
            aq[fi][ig][0] = *(const half8*)qr;
            aq[fi][ig][1] = *(const half8*)(qr+32);
        }
    }
    float lacc[2][2][4];
    #pragma unroll
    for (int fi=0;fi<2;fi++) for (int ig=0;ig<2;ig++) for (int r=0;r<4;r++) lacc[fi][ig][r]=0.f;

    for (int jt = s; jt <= it; jt += 8) {
        int j0 = jt*32;
        #pragma unroll
        for (int fi=0; fi<2; fi++) {
            #pragma unroll
            for (int jh=0; jh<2; jh++) {
                const Hh* kr = kb + (size_t)((b*16+f0+fi)*N_ + j0 + jh*16 + c)*64 + qd*8;
                half8 b0 = *(const half8*)kr;
                half8 b1 = *(const half8*)(kr+32);
                #pragma unroll
                for (int ig=0; ig<2; ig++) {
                    float4v sv = {0.f,0.f,0.f,0.f};
                    sv = __builtin_amdgcn_mfma_f32_16x16x32_f16(aq[fi][ig][0], b0, sv, 0,0,0);
                    sv = __builtin_amdgcn_mfma_f32_16x16x32_f16(aq[fi][ig][1], b1, sv, 0,0,0);
                    #pragma unroll
                    for (int r=0; r<4; r++) {
                        int i = i0 + ig*16 + qd*4 + r;
                        int j = j0 + jh*16 + c;
                        float ev = (j <= i) ? __builtin_amdgcn_exp2f(sv[r]*C1) : 0.f;
                        lacc[fi][ig][r] += ev;
                    }
                }
            }
        }
    }
    #pragma unroll
    for (int fi=0; fi<2; fi++) {
        #pragma unroll
        for (int ig=0; ig<2; ig++) {
            #pragma unroll
            for (int r=0; r<4; r++) {
                float vs = lacc[fi][ig][r];
                vs += __shfl_xor(vs, 1);
                vs += __shfl_xor(vs, 2);
                vs += __shfl_xor(vs, 4);
                vs += __shfl_xor(vs, 8);
                if (c == 0)
                    unsafeAtomicAdd(&lacc_g[(size_t)(b*16+f0+fi)*N_ + i0 + ig*16 + qd*4 + r], vs);
            }
        }
    }
}

// ---------------------------------------------------------------------------
// K3: main fused pass, i-tile 32 / j-tile 32, 1024 thr (16 waves),
// 2 blocks/CU (LDS 80.2 KB, VGPR capped 64 via __launch_bounds__(1024,8)).
// Halves per-(i,j) K/V traffic vs R6 at UNCHANGED 32 waves/CU residency —
// the discriminating test of the ~8.7 TB/s cache-BW-wall theory.
// Roles: scores wave w -> f=w (K frags shared across both ig); mix wave w ->
// jh2=w&1, i-quad 4*(w>>1); PV wave w -> e=w, both ig, 4 nc.
// Grid 1024 = slab-major (s=bid>>7, jt ≡ s mod 8) × descending (b,it64).
// ---------------------------------------------------------------------------
__global__ __launch_bounds__(1024,8) void attend_kernel(const Hh* __restrict__ qb,
    const Hh* __restrict__ kb, const Hh* __restrict__ vt2,
    const float* __restrict__ lacc_g, const float* __restrict__ Wpost,
    float* __restrict__ out)
{
    __shared__ Hh Ebuf[32*EB_JS];   // 41216 B
    __shared__ Hh Pm[16*PM_ES];     // 36992 B
    __shared__ float lgl[512];      // [f(16)][i(32)] log2-denominators, 2 KB

    int bid = blockIdx.x;
    int s = bid >> 7;                        // slab 0..7 (slab-major dispatch)
    int idx = 127 - (bid & 127);
    int b = idx & 1, it = idx >> 1;          // it 0..63, descending
    if (s > it) return;                      // inactive (uniform, pre-barrier)
    int i0 = it * 32;
    int jtmax = it;

    int tid = threadIdx.x;
    int lane = tid & 63, w = tid >> 6;       // w 0..15
    int qd = lane >> 4, c = lane & 15;
    int f = w;                               // scores head
    int e = w;                               // PV head

    // lgl fill (512 entries over 1024 threads)
    if (tid < 512)
        lgl[tid] = __builtin_amdgcn_logf(
            lacc_g[(size_t)(b*16 + (tid>>5))*N_ + i0 + (tid&31)]);

    // Q A-frags for f=w, both ig halves: rows i0+ig*16+c
    half8 aq[2][2];
    #pragma unroll
    for (int ig=0; ig<2; ig++) {
        const Hh* qr = qb + (size_t)((b*16+f)*N_ + i0 + ig*16 + c)*64 + qd*8;
        aq[ig][0] = *(const half8*)qr;
        aq[ig][1] = *(const half8*)(qr+32);
    }
    // W_post B-frag (16x16x16): B[k=f=qd*4+z][n=e=c]
    half4 wf;
    #pragma unroll
    for (int z=0; z<4; z++) wf[z] = (Hh)Wpost[c*16 + qd*4 + z];

    // mix role params
    int jh2 = w & 1, ib = 4*(w>>1);

    float4v acc[2][4];
    #pragma unroll
    for (int ig=0; ig<2; ig++) for (int nc=0; nc<4; nc++)
        acc[ig][nc] = (float4v){0.f,0.f,0.f,0.f};

    auto scores = [&](int jt) {
        int j0 = jt*32;
        const Hh* kbase = kb + (size_t)((b*16+f)*N_ + j0 + c)*64 + qd*8;
        half8 k00 = *(const half8*)kbase;          // jh=0, k 0..31
        half8 k01 = *(const half8*)(kbase+32);     // jh=0, k 32..63
        half8 k10 = *(const half8*)(kbase+1024);   // jh=1 (16 rows * 64)
        half8 k11 = *(const half8*)(kbase+1056);
        #pragma unroll
        for (int ig=0; ig<2; ig++) {
            float4 lg = *(const float4*)&lgl[w*32 + ig*16 + qd*4];
            #pragma unroll
            for (int jh=0; jh<2; jh++) {
                float4v t = {0.f,0.f,0.f,0.f};
                t = __builtin_amdgcn_mfma_f32_16x16x32_f16(aq[ig][0], jh?k10:k00, t, 0,0,0);
                t = __builtin_amdgcn_mfma_f32_16x16x32_f16(aq[ig][1], jh?k11:k01, t, 0,0,0);
                int j = j0 + jh*16 + c;
                #pragma unroll
                for (int r=0; r<4; r++) {
                    int i = i0 + ig*16 + qd*4 + r;
                    float lgr = (&lg.x)[r];
                    float p = (j <= i) ? __builtin_amdgcn_exp2f(t[r]*C1 - lgr) : 0.f;
                    Ebuf[(jh*16+c)*EB_JS + (ig*16+qd*4+r)*EB_IS + f] = (Hh)p;
                }
            }
        }
    };

    __syncthreads();      // lgl ready (full sync incl. vmcnt fine here, once)
    scores(s);
    BAR();

    for (int jt = s; jt <= jtmax; jt += 8) {
        // ---- head mix: wave w -> (jh2, i-rows ib..ib+3) ----
        #pragma unroll
        for (int ii=0; ii<4; ii++) {
            int i = ib + ii;
            half4 ef = *(const half4*)&Ebuf[(jh2*16+c)*EB_JS + i*EB_IS + qd*4];
            float4v cc = {0.f,0.f,0.f,0.f};
            cc = __builtin_amdgcn_mfma_f32_16x16x16f16(ef, wf, cc, 0,0,0);
            half4 hv;
            #pragma unroll
            for (int r=0; r<4; r++) hv[r] = (Hh)cc[r];
            *(half4*)&Pm[c*PM_ES + i*PM_IS + jh2*16 + qd*4] = hv;
        }
        BAR();
        // ---- PV(jt) for e=w (both ig), overlapped with scores(jt+8) ----
        #pragma unroll
        for (int ig=0; ig<2; ig++) {
            half8 pa = *(const half8*)&Pm[e*PM_ES + (ig*16+c)*PM_IS + qd*8];
            #pragma unroll
            for (int nc=0; nc<4; nc++) {
                const Hh* vr = vt2 + (size_t)((b*16+e)*64 + jt)*2048 + (nc*16+c)*32 + qd*8;
                half8 vb = *(const half8*)vr;
                acc[ig][nc] = __builtin_amdgcn_mfma_f32_16x16x32_f16(pa, vb, acc[ig][nc], 0,0,0);
            }
        }
        if (jt + 8 <= jtmax) scores(jt + 8);
        BAR();
    }

    // ---- accumulate partial O (nc order rotated by slab to stagger RMW) ----
    #pragma unroll
    for (int ig=0; ig<2; ig++) {
        #pragma unroll
        for (int nc0=0; nc0<4; nc0++) {
            int nc = (nc0 + s) & 3;
            #pragma unroll
            for (int r=0; r<4; r++)
                unsafeAtomicAdd(&out[(size_t)((b*16+e)*N_ + i0 + ig*16 + qd*4 + r)*64 + nc*16 + c],
                                acc[ig][nc][r]);
        }
    }
}

extern "C" void kernel_launch(void* const* d_in, const int* in_sizes, int n_in,
                              void* d_out, int out_size, void* d_ws, size_t ws_size,
                              hipStream_t stream) {
    const float* q     = (const float*)d_in[0];
    const float* k     = (const float*)d_in[1];
    const float* v     = (const float*)d_in[2];
    const float* Wpre  = (const float*)d_in[3];
    const float* Wpost = (const float*)d_in[4];
    float* out = (float*)d_out;

    size_t tsz = (size_t)B_*H_*N_*D_;       // 4 Mi halves = 8 MB each
    Hh* qb = (Hh*)d_ws;
    Hh* kb = qb + tsz;
    Hh* vt2 = kb + tsz;
    float* lacc = (float*)(vt2 + tsz);      // 24 MB offset, 256 KB

    prep_kernel<<<1792, 256, 0, stream>>>(q, k, v, Wpre, qb, kb, vt2,
                                          (float4*)out, (float4*)lacc);
    denom_kernel<<<1024, 512, 0, stream>>>(qb, kb, lacc);
    attend_kernel<<<1024, 1024, 0, stream>>>(qb, kb, vt2, lacc, Wpost, out);
}